// Round 11
// baseline (463.990 us; speedup 1.0000x reference)
//
#include <hip/hip_runtime.h>
#include <hip/hip_bf16.h>
#include <hip/hip_cooperative_groups.h>
#include <type_traits>

namespace cg = cooperative_groups;

#define NN   8000
#define NE   64000
#define NE2  72000   // edges + self loops
#define NH   8
#define OC   512
#define HC   4096    // NH*OC
#define KIN  128
#define NOUT 512
#define YW   1024    // NH*KIN
#define NEG_SLOPE 0.2f
#define WCSK 4       // split-K planes for Wc GEMM

// phase virtual-block counts
#define TCVT_NB   2048
#define VSRC_BASE 2048
#define CNT_BASE  2176
#define P1_NB     2458
#define P2_NB     257      // 256 wc tiles + 1 scan
#define FILL_NB   282
#define P3_NB     782      // fill + 500 attn2
#define AGG_NB    2000
#define P4_NB     2256     // agg + 256 WcT-reduce
#define P5_NB     500      // final gemm 125 x 4

using bf16 = __hip_bfloat16;
typedef float  f32x4  __attribute__((ext_vector_type(4)));
typedef __bf16 bf16x8 __attribute__((ext_vector_type(8)));

static __device__ __forceinline__ void gld_lds16(const bf16* g, bf16* l){
    __builtin_amdgcn_global_load_lds(
        (const __attribute__((address_space(1))) unsigned int*)g,
        (__attribute__((address_space(3))) unsigned int*)l, 16, 0, 0);
}

struct Acc24 { f32x4 a[2][4]; };

// 64x128 MFMA tile, LDS double-buffered. A: 64 rows (pre-offset), lda; BT: 128 rows, ldb.
static __device__ __forceinline__ void gemm64x128(
    const bf16* __restrict__ A, int lda, const bf16* __restrict__ BT, int ldb,
    int K, bf16* sA, bf16* sB, int tid, Acc24& acc)
{
    const int lane = tid & 63;
    const int w    = tid >> 6;
    const int wm   = w >> 1, wn = w & 1;
    const int m16  = lane & 15, q = lane >> 4;
    const int rA = tid >> 2,  kA = (tid & 3) * 8;
    const int cB0 = tid, cB1 = 256 + tid;
    const int rB0 = cB0 >> 2, kB0 = (cB0 & 3) * 8;
    const int rB1 = cB1 >> 2, kB1 = (cB1 & 3) * 8;
    const size_t gA  = (size_t)rA  * lda + kA;
    const size_t gB0 = (size_t)rB0 * ldb + kB0;
    const size_t gB1 = (size_t)rB1 * ldb + kB1;

    #pragma unroll
    for (int i=0;i<2;++i)
        #pragma unroll
        for (int j=0;j<4;++j)
            #pragma unroll
            for (int r=0;r<4;++r) acc.a[i][j][r] = 0.f;

    gld_lds16(A  + gA,  sA + tid*8);
    gld_lds16(BT + gB0, sB + cB0*8);
    gld_lds16(BT + gB1, sB + cB1*8);
    __syncthreads();

    const int nIter = K / 32;
    for (int it = 0; it < nIter; ++it){
        const int cur = it & 1, nxt = cur ^ 1;
        bf16x8 af[2], bfr[4];
        #pragma unroll
        for (int i=0;i<2;++i)
            af[i]  = *(const bf16x8*)(const void*)(sA + cur*64*32 + ((wm*32 + i*16 + m16)*32 + q*8));
        #pragma unroll
        for (int j=0;j<4;++j)
            bfr[j] = *(const bf16x8*)(const void*)(sB + cur*128*32 + ((wn*64 + j*16 + m16)*32 + q*8));
        if (it + 1 < nIter){
            int ko = (it+1) * 32;
            gld_lds16(A  + gA  + ko, sA + nxt*64*32 + tid*8);
            gld_lds16(BT + gB0 + ko, sB + nxt*128*32 + cB0*8);
            gld_lds16(BT + gB1 + ko, sB + nxt*128*32 + cB1*8);
        }
        #pragma unroll
        for (int i=0;i<2;++i)
            #pragma unroll
            for (int j=0;j<4;++j)
                acc.a[i][j] = __builtin_amdgcn_mfma_f32_16x16x32_bf16(af[i], bfr[j], acc.a[i][j], 0, 0, 0);
        __syncthreads();
    }
}

__global__ __launch_bounds__(256, 4) void k_mega(
    const float* __restrict__ x, const int* __restrict__ eidx,
    const float* __restrict__ W_gat, const float* __restrict__ b_gat,
    const float* __restrict__ att_src, const float* __restrict__ att_dst,
    const float* __restrict__ W_lin, const float* __restrict__ b_lin,
    float* __restrict__ out,
    bf16* __restrict__ Wl_t, bf16* __restrict__ Wg_bf,
    bf16* __restrict__ WcT, bf16* __restrict__ Ybuf,
    float* __restrict__ partW, float* __restrict__ v,
    float* __restrict__ a_src, float* __restrict__ a_dst,
    int* __restrict__ offs, int* __restrict__ esrc,
    int* __restrict__ zero_base)   // counts | cursors | b_eff (contiguous)
{
    cg::grid_group grid = cg::this_grid();
    __shared__ __align__(16) char smem_raw[24576];   // union over phases
    int*   counts  = zero_base;
    int*   cursors = zero_base + NN;
    float* b_eff   = (float*)(zero_base + 2*NN);
    const int tid = threadIdx.x;
    const int nb  = gridDim.x;

    // ---------- P0: zero counts + cursors + b_eff ----------
    for (int i = blockIdx.x*256 + tid; i < 2*NN + NOUT; i += nb*256)
        zero_base[i] = 0;
    grid.sync();

    // ---------- P1: W_lin tcvt + b_eff | W_gat cvt + v | edge count ----------
    for (int vb = blockIdx.x; vb < P1_NB; vb += nb){
        if (vb < TCVT_NB){
            float (*t)[33] = (float(*)[33])smem_raw;
            float* bpart = (float*)smem_raw + 32*33;
            if (tid < 32) bpart[tid] = 0.f;
            __syncthreads();
            int tx = tid & 31, ty = tid >> 5;
            int n0 = (vb & 15)*32, k0 = (vb >> 4)*32;
            float pb = 0.f;
            #pragma unroll
            for (int i=0;i<4;++i){
                int k = k0 + ty + 8*i;
                float val = W_lin[(size_t)k*NOUT + n0 + tx];
                t[ty+8*i][tx] = val;
                pb = fmaf(b_gat[k], val, pb);
            }
            atomicAdd(&bpart[tx], pb);
            __syncthreads();
            #pragma unroll
            for (int i=0;i<4;++i)
                Wl_t[(size_t)(n0+ty+8*i)*HC + k0+tx] = __float2bfloat16(t[tx][ty+8*i]);
            if (tid < 32) atomicAdd(b_eff + n0 + tid, bpart[tid]);
            __syncthreads();
        } else if (vb < CNT_BASE){
            int k = vb - VSRC_BASE;
            int lane = tid & 63, g = tid >> 6;
            for (int hh = g; hh < NH; hh += 4){
                const float* wp = W_gat + (size_t)k*HC + hh*OC;
                bf16*        wb = Wg_bf + (size_t)k*HC + hh*OC;
                const float* as = att_src + hh*OC;
                const float* ad = att_dst + hh*OC;
                float ss = 0.f, sd = 0.f;
                #pragma unroll
                for (int c0=0; c0<OC; c0+=64){
                    float wv = wp[c0+lane];
                    wb[c0+lane] = __float2bfloat16(wv);
                    ss = fmaf(wv, as[c0+lane], ss);
                    sd = fmaf(wv, ad[c0+lane], sd);
                }
                #pragma unroll
                for (int off=32; off; off>>=1){
                    ss += __shfl_down(ss, off);
                    sd += __shfl_down(sd, off);
                }
                if (lane == 0){
                    v[k*16 + hh]     = ss;
                    v[k*16 + 8 + hh] = sd;
                }
            }
        } else {
            int e = (vb - CNT_BASE)*256 + tid;
            if (e < NE2){
                int dst = (e < NE) ? eidx[NE + e] : (e - NE);
                atomicAdd(&counts[dst], 1);
            }
        }
    }
    grid.sync();

    // ---------- P2: Wc split-K GEMM (256 x 64x128 tiles) + CSR scan ----------
    for (int vb = blockIdx.x; vb < P2_NB; vb += nb){
        if (vb < 256){
            bf16* sA = (bf16*)smem_raw;                 // [2][64*32]
            bf16* sB = (bf16*)(smem_raw + 8192);        // [2][128*32]
            int head = vb >> 5, sp = (vb >> 3) & 3, mt = vb & 7;
            const bf16* A  = Wl_t  + head*OC + sp*128 + (size_t)(mt*64)*HC;
            const bf16* BT = Wg_bf + head*OC + sp*128;
            Acc24 acc;
            gemm64x128(A, HC, BT, HC, 128, sA, sB, tid, acc);
            const int lane = tid & 63;
            const int w = tid >> 6, wm = w >> 1, wn = w & 1;
            const int m16 = lane & 15, q = lane >> 4;
            float* pout = partW + (size_t)sp*NOUT*YW + head*KIN;
            #pragma unroll
            for (int i=0;i<2;++i){
                int o_base = mt*64 + wm*32 + i*16 + q*4;
                #pragma unroll
                for (int j=0;j<4;++j){
                    int col = wn*64 + j*16 + m16;
                    #pragma unroll
                    for (int r=0;r<4;++r)
                        pout[(size_t)(o_base + r)*YW + col] = acc.a[i][j][r];
                }
            }
        } else {
            int* part = (int*)smem_raw;
            int t = tid;
            int base = t*32;
            int s = 0;
            for (int u=0;u<32;++u){ int i = base+u; if (i<NN) s += counts[i]; }
            part[t] = s;
            __syncthreads();
            for (int off=1; off<256; off<<=1){
                int vv = (t>=off) ? part[t-off] : 0;
                __syncthreads();
                part[t] += vv;
                __syncthreads();
            }
            int run = (t==0) ? 0 : part[t-1];
            for (int u=0;u<32;++u){
                int i = base+u;
                if (i<NN){ offs[i] = run; run += counts[i]; }
            }
            if (t == 255) offs[NN] = run;
            __syncthreads();
        }
    }
    grid.sync();

    // ---------- P3: CSR fill + attn2 ----------
    for (int vb = blockIdx.x; vb < P3_NB; vb += nb){
        if (vb < FILL_NB){
            int e = vb*256 + tid;
            if (e < NE2){
                int src, dst;
                if (e < NE){ src = eidx[e]; dst = eidx[NE+e]; } else { src = dst = e - NE; }
                int pos = atomicAdd(&cursors[dst], 1);
                esrc[offs[dst] + pos] = src;
            }
        } else {
            float (*xs)[132] = (float(*)[132])smem_raw;
            float (*vt)[132] = (float(*)[132])((float*)smem_raw + 16*132);
            int node0 = (vb - FILL_NB) * 16;
            {
                const float* xg = x + (size_t)node0*KIN;
                int row = tid >> 4, co = (tid & 15) * 8;
                float4 v0 = *(const float4*)(xg + row*KIN + co);
                float4 v1 = *(const float4*)(xg + row*KIN + co + 4);
                *(float4*)&xs[row][co]     = v0;
                *(float4*)&xs[row][co + 4] = v1;
            }
            {
                int base = tid*8;
                #pragma unroll
                for (int j=0;j<8;++j){
                    int idx = base + j;
                    vt[idx & 15][idx >> 4] = v[idx];
                }
            }
            __syncthreads();
            int ln = tid >> 4, o = tid & 15;
            float acc = 0.f;
            #pragma unroll
            for (int k0=0;k0<KIN;k0+=4){
                float4 xv = *(const float4*)&xs[ln][k0];
                float4 vv = *(const float4*)&vt[o][k0];
                acc += xv.x*vv.x + xv.y*vv.y + xv.z*vv.z + xv.w*vv.w;
            }
            int node = node0 + ln;
            if (o < 8) a_src[node*NH + o]     = acc;
            else       a_dst[node*NH + o - 8] = acc;
            __syncthreads();
        }
    }
    grid.sync();

    // ---------- P4: Y aggregation + WcT reduce ----------
    for (int vb = blockIdx.x; vb < P4_NB; vb += nb){
        if (vb >= AGG_NB){
            int t = (vb - AGG_NB)*256 + tid;
            int base = t*8;
            float s[8];
            #pragma unroll
            for (int j=0;j<8;++j) s[j] = 0.f;
            #pragma unroll
            for (int sp=0; sp<WCSK; ++sp){
                const float4* pp = (const float4*)(partW + (size_t)sp*NOUT*YW + base);
                float4 p0 = pp[0], p1 = pp[1];
                s[0]+=p0.x; s[1]+=p0.y; s[2]+=p0.z; s[3]+=p0.w;
                s[4]+=p1.x; s[5]+=p1.y; s[6]+=p1.z; s[7]+=p1.w;
            }
            bf16x8 o;
            #pragma unroll
            for (int j=0;j<8;++j) o[j] = (__bf16)s[j];
            *(bf16x8*)(void*)(WcT + base) = o;
        } else {
            int node = vb*4 + (tid >> 6);
            int lane = tid & 63;
            int s0 = offs[node], s1 = offs[node+1];
            int g = lane >> 3, h = lane & 7;
            float adl = a_dst[node*NH + h];
            float m = -1e30f, sum = 0.f;
            for (int e = s0 + g; e < s1; e += 8){
                float l = a_src[esrc[e]*NH + h] + adl;
                l = l > 0.f ? l : NEG_SLOPE*l;
                float mn = fmaxf(m, l);
                sum = sum*__expf(m - mn) + __expf(l - mn);
                m = mn;
            }
            #pragma unroll
            for (int d=8; d<64; d<<=1){
                float mo = __shfl_xor(m, d);
                float so = __shfl_xor(sum, d);
                float mn = fmaxf(m, mo);
                sum = sum*__expf(m - mn) + so*__expf(mo - mn);
                m = mn;
            }
            float inv = 1.f / (sum + 1e-16f);
            float acc[16];
            #pragma unroll
            for (int j=0;j<16;++j) acc[j] = 0.f;
            for (int s=s0; s<s1; ++s){
                int src = esrc[s];
                float wl = 0.f;
                if (lane < 8){
                    float l = a_src[src*NH + lane] + adl;
                    l = l > 0.f ? l : NEG_SLOPE*l;
                    wl = __expf(l - m) * inv;
                }
                float2 xv = *(const float2*)(x + (size_t)src*KIN + lane*2);
                #pragma unroll
                for (int hh=0; hh<8; ++hh){
                    float wh = __shfl(wl, hh);
                    acc[hh*2]   = fmaf(wh, xv.x, acc[hh*2]);
                    acc[hh*2+1] = fmaf(wh, xv.y, acc[hh*2+1]);
                }
            }
            bf16* yp = Ybuf + (size_t)node*YW + lane*2;
            #pragma unroll
            for (int hh=0; hh<8; ++hh){
                bf16 b0 = __float2bfloat16(acc[hh*2]);
                bf16 b1 = __float2bfloat16(acc[hh*2+1]);
                ushort2 pk;
                pk.x = *(unsigned short*)&b0;
                pk.y = *(unsigned short*)&b1;
                *reinterpret_cast<ushort2*>(yp + hh*KIN) = pk;
            }
        }
    }
    grid.sync();

    // ---------- P5: out = Y @ WcT^T + b_eff + b_lin ----------
    for (int vb = blockIdx.x; vb < P5_NB; vb += nb){
        bf16* sA = (bf16*)smem_raw;
        bf16* sB = (bf16*)(smem_raw + 8192);
        int m0 = (vb % 125) * 64;
        int n0 = (vb / 125) * 128;
        const bf16* A  = Ybuf + (size_t)m0*YW;
        const bf16* BT = WcT  + (size_t)n0*YW;
        Acc24 acc;
        gemm64x128(A, YW, BT, YW, YW, sA, sB, tid, acc);
        const int lane = tid & 63;
        const int w = tid >> 6, wm = w >> 1, wn = w & 1;
        const int m16 = lane & 15, q = lane >> 4;
        #pragma unroll
        for (int i=0;i<2;++i){
            int row_base = m0 + wm*32 + i*16 + q*4;
            #pragma unroll
            for (int j=0;j<4;++j){
                int col = n0 + wn*64 + j*16 + m16;
                float bval = b_eff[col] + b_lin[col];
                #pragma unroll
                for (int r=0;r<4;++r)
                    out[(size_t)(row_base + r)*NOUT + col] = acc.a[i][j][r] + bval;
            }
        }
    }
}

extern "C" void kernel_launch(void* const* d_in, const int* in_sizes, int n_in,
                              void* d_out, int out_size, void* d_ws, size_t ws_size,
                              hipStream_t stream)
{
    const float* x       = (const float*)d_in[0];
    const int*   eidx    = (const int*)  d_in[1];
    const float* W_gat   = (const float*)d_in[2];
    const float* b_gat   = (const float*)d_in[3];
    const float* att_src = (const float*)d_in[4];
    const float* att_dst = (const float*)d_in[5];
    const float* W_lin   = (const float*)d_in[6];
    const float* b_lin   = (const float*)d_in[7];
    float* out = (float*)d_out;

    char* p = (char*)d_ws;
    auto alloc = [&](size_t bytes){ void* r = (void*)p; p += (bytes + 255) & ~(size_t)255; return r; };
    bf16*  Wg_bf  = (bf16*) alloc((size_t)KIN*HC*2);        // 1 MB
    bf16*  Wl_t   = (bf16*) alloc((size_t)NOUT*HC*2);       // 4 MB
    bf16*  WcT    = (bf16*) alloc((size_t)NOUT*YW*2);       // 1 MB
    bf16*  Ybuf   = (bf16*) alloc((size_t)NN*YW*2);         // 16.4 MB
    float* partW  = (float*)alloc((size_t)WCSK*NOUT*YW*4);  // 8.4 MB
    float* v      = (float*)alloc((size_t)KIN*16*4);
    float* a_src  = (float*)alloc((size_t)NN*NH*4);
    float* a_dst  = (float*)alloc((size_t)NN*NH*4);
    int*   offs   = (int*)  alloc((size_t)(NN+1)*4);
    int*   esrc   = (int*)  alloc((size_t)NE2*4);
    int*   zb     = (int*)  alloc((size_t)(2*NN + NOUT)*4); // counts|cursors|b_eff
    if ((size_t)(p - (char*)d_ws) > ws_size) return;

    int maxB = 0;
    hipOccupancyMaxActiveBlocksPerMultiprocessor(&maxB, k_mega, 256, 0);
    int nblocks = maxB * 256;                 // co-resident guarantee
    if (nblocks > 1024) nblocks = 1024;
    if (nblocks < 256)  nblocks = (maxB > 0) ? maxB*256 : 256;

    void* args[] = {
        (void*)&x, (void*)&eidx, (void*)&W_gat, (void*)&b_gat,
        (void*)&att_src, (void*)&att_dst, (void*)&W_lin, (void*)&b_lin,
        (void*)&out, (void*)&Wl_t, (void*)&Wg_bf, (void*)&WcT, (void*)&Ybuf,
        (void*)&partW, (void*)&v, (void*)&a_src, (void*)&a_dst,
        (void*)&offs, (void*)&esrc, (void*)&zb
    };
    hipLaunchCooperativeKernel((const void*)k_mega, dim3(nblocks), dim3(256),
                               args, 0, stream);
}

// Round 13
// 147.541 us; speedup vs baseline: 3.1448x; 3.1448x over previous
//
#include <hip/hip_runtime.h>
#include <hip/hip_bf16.h>
#include <type_traits>

#define NN   8000
#define NE   64000
#define NE2  72000   // edges + self loops
#define NH   8
#define OC   512
#define HC   4096    // NH*OC
#define KIN  128
#define NOUT 512
#define YW   1024    // NH*KIN
#define NEG_SLOPE 0.2f

using bf16 = __hip_bfloat16;
typedef float  f32x4  __attribute__((ext_vector_type(4)));
typedef __bf16 bf16x8 __attribute__((ext_vector_type(8)));

static __device__ __forceinline__ void gld_lds16(const bf16* g, bf16* l){
    __builtin_amdgcn_global_load_lds(
        (const __attribute__((address_space(1))) unsigned int*)g,
        (__attribute__((address_space(3))) unsigned int*)l, 16, 0, 0);
}

struct Acc24 { f32x4 a[2][4]; };

// 64x128 MFMA tile, LDS double-buffered. A: 64 rows (pre-offset), lda; BT: 128 rows, ldb.
static __device__ __forceinline__ void gemm64x128(
    const bf16* __restrict__ A, int lda, const bf16* __restrict__ BT, int ldb,
    int K, bf16* sA, bf16* sB, int tid, Acc24& acc)
{
    const int lane = tid & 63;
    const int w    = tid >> 6;
    const int wm   = w >> 1, wn = w & 1;
    const int m16  = lane & 15, q = lane >> 4;
    const int rA = tid >> 2,  kA = (tid & 3) * 8;
    const int cB0 = tid, cB1 = 256 + tid;
    const int rB0 = cB0 >> 2, kB0 = (cB0 & 3) * 8;
    const int rB1 = cB1 >> 2, kB1 = (cB1 & 3) * 8;
    const size_t gA  = (size_t)rA  * lda + kA;
    const size_t gB0 = (size_t)rB0 * ldb + kB0;
    const size_t gB1 = (size_t)rB1 * ldb + kB1;

    #pragma unroll
    for (int i=0;i<2;++i)
        #pragma unroll
        for (int j=0;j<4;++j)
            #pragma unroll
            for (int r=0;r<4;++r) acc.a[i][j][r] = 0.f;

    gld_lds16(A  + gA,  sA + tid*8);
    gld_lds16(BT + gB0, sB + cB0*8);
    gld_lds16(BT + gB1, sB + cB1*8);
    __syncthreads();

    const int nIter = K / 32;
    for (int it = 0; it < nIter; ++it){
        const int cur = it & 1, nxt = cur ^ 1;
        bf16x8 af[2], bfr[4];
        #pragma unroll
        for (int i=0;i<2;++i)
            af[i]  = *(const bf16x8*)(const void*)(sA + cur*64*32 + ((wm*32 + i*16 + m16)*32 + q*8));
        #pragma unroll
        for (int j=0;j<4;++j)
            bfr[j] = *(const bf16x8*)(const void*)(sB + cur*128*32 + ((wn*64 + j*16 + m16)*32 + q*8));
        if (it + 1 < nIter){
            int ko = (it+1) * 32;
            gld_lds16(A  + gA  + ko, sA + nxt*64*32 + tid*8);
            gld_lds16(BT + gB0 + ko, sB + nxt*128*32 + cB0*8);
            gld_lds16(BT + gB1 + ko, sB + nxt*128*32 + cB1*8);
        }
        #pragma unroll
        for (int i=0;i<2;++i)
            #pragma unroll
            for (int j=0;j<4;++j)
                acc.a[i][j] = __builtin_amdgcn_mfma_f32_16x16x32_bf16(af[i], bfr[j], acc.a[i][j], 0, 0, 0);
        __syncthreads();
    }
}

// ================= phase A: independent preprocessing (round-10 verbatim) =================
// [0,2048): W_lin transpose->bf16 + b_eff partials
// [2048,2176): W_gat->bf16 + v[k][o]
// [2176,2458): edge dst count
#define TCVT_NB   2048
#define VSRC_BASE 2048
#define CNT_BASE  2176
#define PHA_NB    2458

__global__ __launch_bounds__(256) void k_phaseA(
    const float* __restrict__ W_lin, const float* __restrict__ b_gat,
    const float* __restrict__ W_gat,
    const float* __restrict__ att_src, const float* __restrict__ att_dst,
    const int* __restrict__ eidx,
    bf16* __restrict__ Wl_t, float* __restrict__ b_eff,
    bf16* __restrict__ Wg_bf, float* __restrict__ v,
    int* __restrict__ counts)
{
    __shared__ __align__(16) float smem[32*33 + 32];
    const int bid = blockIdx.x;
    const int tid = threadIdx.x;

    if (bid < TCVT_NB){
        float (*t)[33] = (float(*)[33])smem;
        float* bpart = smem + 32*33;
        if (tid < 32) bpart[tid] = 0.f;
        __syncthreads();
        int tx = tid & 31, ty = tid >> 5;
        int n0 = (bid & 15) * 32, k0 = (bid >> 4) * 32;
        float pb = 0.f;
        #pragma unroll
        for (int i=0;i<4;++i){
            int k = k0 + ty + 8*i;
            float val = W_lin[(size_t)k*NOUT + n0 + tx];
            t[ty+8*i][tx] = val;
            pb = fmaf(b_gat[k], val, pb);
        }
        atomicAdd(&bpart[tx], pb);
        __syncthreads();
        #pragma unroll
        for (int i=0;i<4;++i)
            Wl_t[(size_t)(n0+ty+8*i)*HC + k0+tx] = __float2bfloat16(t[tx][ty+8*i]);
        if (tid < 32) atomicAdd(b_eff + n0 + tid, bpart[tid]);
    } else if (bid < CNT_BASE){
        int k = bid - VSRC_BASE;
        int lane = tid & 63, g = tid >> 6;
        for (int hh = g; hh < NH; hh += 4){
            const float* wp = W_gat + (size_t)k*HC + hh*OC;
            bf16*        wb = Wg_bf + (size_t)k*HC + hh*OC;
            const float* as = att_src + hh*OC;
            const float* ad = att_dst + hh*OC;
            float ss = 0.f, sd = 0.f;
            #pragma unroll
            for (int c0=0; c0<OC; c0+=64){
                float wv = wp[c0+lane];
                wb[c0+lane] = __float2bfloat16(wv);
                ss = fmaf(wv, as[c0+lane], ss);
                sd = fmaf(wv, ad[c0+lane], sd);
            }
            #pragma unroll
            for (int off=32; off; off>>=1){
                ss += __shfl_down(ss, off);
                sd += __shfl_down(sd, off);
            }
            if (lane == 0){
                v[k*16 + hh]     = ss;
                v[k*16 + 8 + hh] = sd;
            }
        }
    } else {
        int e = (bid - CNT_BASE)*256 + tid;
        if (e < NE2){
            int dst = (e < NE) ? eidx[NE + e] : (e - NE);
            atomicAdd(&counts[dst], 1);
        }
    }
}

// ================= phase B: Wc GEMM direct (64 blocks) + CSR scan (1 block) =========
// bid<64: head = bid>>3, mt = bid&7; WcT[o][h*128+k] = sum_c Wl_t[o][h*512+c]*Wg_bf[k][h*512+c]
__global__ __launch_bounds__(256) void k_phaseB(
    const bf16* __restrict__ Wl_t, const bf16* __restrict__ Wg_bf,
    bf16* __restrict__ WcT,
    const int* __restrict__ counts, int* __restrict__ offsets)
{
    __shared__ __align__(16) char smem_raw[24576];
    __shared__ int part[256];
    const int bid = blockIdx.x;
    const int tid = threadIdx.x;

    if (bid == 64){
        int t = tid;
        int base = t*32;
        int s = 0;
        for (int u=0;u<32;++u){ int i = base+u; if (i<NN) s += counts[i]; }
        part[t] = s;
        __syncthreads();
        for (int off=1; off<256; off<<=1){
            int vv = (t>=off) ? part[t-off] : 0;
            __syncthreads();
            part[t] += vv;
            __syncthreads();
        }
        int run = (t==0) ? 0 : part[t-1];
        for (int u=0;u<32;++u){
            int i = base+u;
            if (i<NN){ offsets[i] = run; run += counts[i]; }
        }
        if (t == 255) offsets[NN] = run;
        return;
    }

    bf16* sA = (bf16*)smem_raw;             // [2][64*32]  8 KB
    bf16* sB = (bf16*)(smem_raw + 8192);    // [2][128*32] 16 KB
    const int head = bid >> 3, mt = bid & 7;
    const bf16* A  = Wl_t  + head*OC + (size_t)(mt*64)*HC;
    const bf16* BT = Wg_bf + head*OC;
    Acc24 acc;
    gemm64x128(A, HC, BT, HC, OC, sA, sB, tid, acc);
    const int lane = tid & 63;
    const int w = tid >> 6, wm = w >> 1, wn = w & 1;
    const int m16 = lane & 15, q = lane >> 4;
    #pragma unroll
    for (int i=0;i<2;++i){
        int o_base = mt*64 + wm*32 + i*16 + q*4;
        #pragma unroll
        for (int j=0;j<4;++j){
            int col = head*KIN + wn*64 + j*16 + m16;
            #pragma unroll
            for (int r=0;r<4;++r)
                WcT[(size_t)(o_base + r)*YW + col] = __float2bfloat16(acc.a[i][j][r]);
        }
    }
}

// ================= phase C: CSR fill (282) + attn2 (500) (round-10 verbatim) =========
#define FILL_NB 282
#define PHC_NB  782

__global__ __launch_bounds__(256) void k_phaseC(
    const int* __restrict__ eidx, const int* __restrict__ offsets,
    int* __restrict__ cursors, int* __restrict__ esrc,
    const float* __restrict__ x, const float* __restrict__ v,
    float* __restrict__ a_src, float* __restrict__ a_dst)
{
    __shared__ __align__(16) float smem[16*132*2];
    const int bid = blockIdx.x;
    const int tid = threadIdx.x;

    if (bid < FILL_NB){
        int e = bid*256 + tid;
        if (e < NE2){
            int src, dst;
            if (e < NE){ src = eidx[e]; dst = eidx[NE+e]; } else { src = dst = e - NE; }
            int pos = atomicAdd(&cursors[dst], 1);
            esrc[offsets[dst] + pos] = src;
        }
        return;
    }
    float (*xs)[132] = (float(*)[132])smem;
    float (*vt)[132] = (float(*)[132])(smem + 16*132);
    int node0 = (bid - FILL_NB) * 16;
    {
        const float* xg = x + (size_t)node0*KIN;
        int row = tid >> 4, co = (tid & 15) * 8;
        float4 v0 = *(const float4*)(xg + row*KIN + co);
        float4 v1 = *(const float4*)(xg + row*KIN + co + 4);
        *(float4*)&xs[row][co]     = v0;
        *(float4*)&xs[row][co + 4] = v1;
    }
    {
        int base = tid*8;
        #pragma unroll
        for (int j=0;j<8;++j){
            int idx = base + j;
            vt[idx & 15][idx >> 4] = v[idx];
        }
    }
    __syncthreads();
    int ln = tid >> 4, o = tid & 15;
    float acc = 0.f;
    #pragma unroll
    for (int k0=0;k0<KIN;k0+=4){
        float4 xv = *(const float4*)&xs[ln][k0];
        float4 vv = *(const float4*)&vt[o][k0];
        acc += xv.x*vv.x + xv.y*vv.y + xv.z*vv.z + xv.w*vv.w;
    }
    int node = node0 + ln;
    if (o < 8) a_src[node*NH + o]     = acc;
    else       a_dst[node*NH + o - 8] = acc;
}

// ================= Y aggregation (round-10 verbatim agg path, fp32 x gather) =========
__global__ __launch_bounds__(256) void k_agg(const int* __restrict__ offs,
    const int* __restrict__ esrc, const float* __restrict__ a_src,
    const float* __restrict__ a_dst, const float* __restrict__ x,
    bf16* __restrict__ Y)
{
    int node = blockIdx.x*4 + (threadIdx.x >> 6);
    int lane = threadIdx.x & 63;
    int s0 = offs[node], s1 = offs[node+1];
    int g = lane >> 3, h = lane & 7;
    float adl = a_dst[node*NH + h];
    // parallel online max/sum: 8 edge-groups x 8 heads
    float m = -1e30f, sum = 0.f;
    for (int e = s0 + g; e < s1; e += 8){
        float l = a_src[esrc[e]*NH + h] + adl;
        l = l > 0.f ? l : NEG_SLOPE*l;
        float mn = fmaxf(m, l);
        sum = sum*__expf(m - mn) + __expf(l - mn);
        m = mn;
    }
    #pragma unroll
    for (int d=8; d<64; d<<=1){
        float mo = __shfl_xor(m, d);
        float so = __shfl_xor(sum, d);
        float mn = fmaxf(m, mo);
        sum = sum*__expf(m - mn) + so*__expf(mo - mn);
        m = mn;
    }
    float inv = 1.f / (sum + 1e-16f);
    float acc[16];
    #pragma unroll
    for (int j=0;j<16;++j) acc[j] = 0.f;
    for (int s=s0; s<s1; ++s){
        int src = esrc[s];
        float wl = 0.f;
        if (lane < 8){
            float l = a_src[src*NH + lane] + adl;
            l = l > 0.f ? l : NEG_SLOPE*l;
            wl = __expf(l - m) * inv;
        }
        float2 xv = *(const float2*)(x + (size_t)src*KIN + lane*2);
        #pragma unroll
        for (int hh=0; hh<8; ++hh){
            float wh = __shfl(wl, hh);
            acc[hh*2]   = fmaf(wh, xv.x, acc[hh*2]);
            acc[hh*2+1] = fmaf(wh, xv.y, acc[hh*2+1]);
        }
    }
    bf16* yp = Y + (size_t)node*YW + lane*2;
    #pragma unroll
    for (int hh=0; hh<8; ++hh){
        bf16 b0 = __float2bfloat16(acc[hh*2]);
        bf16 b1 = __float2bfloat16(acc[hh*2+1]);
        ushort2 pk;
        pk.x = *(unsigned short*)&b0;
        pk.y = *(unsigned short*)&b1;
        *reinterpret_cast<ushort2*>(yp + hh*KIN) = pk;
    }
}

// ================= final GEMM: out = Y @ WcT^T + b_eff + b_lin (round-10 verbatim) ===
__global__ __launch_bounds__(256) void k_gemm64(
    const bf16* __restrict__ A, const bf16* __restrict__ BT,
    const float* __restrict__ b_eff, const float* __restrict__ b_lin,
    float* __restrict__ C)
{
    __shared__ __align__(16) char smem_raw[24576];
    bf16* sA = (bf16*)smem_raw;
    bf16* sB = (bf16*)(smem_raw + 8192);
    const int tid = threadIdx.x;
    int m0 = blockIdx.x * 64;
    int n0 = blockIdx.y * 128;
    Acc24 acc;
    gemm64x128(A + (size_t)m0*YW, YW, BT + (size_t)n0*YW, YW, YW, sA, sB, tid, acc);
    const int lane = tid & 63;
    const int w = tid >> 6, wm = w >> 1, wn = w & 1;
    const int m16 = lane & 15, q = lane >> 4;
    #pragma unroll
    for (int i=0;i<2;++i){
        int row_base = m0 + wm*32 + i*16 + q*4;
        #pragma unroll
        for (int j=0;j<4;++j){
            int col = n0 + wn*64 + j*16 + m16;
            float bval = b_eff[col] + b_lin[col];
            #pragma unroll
            for (int r=0;r<4;++r)
                C[(size_t)(row_base + r)*NOUT + col] = acc.a[i][j][r] + bval;
        }
    }
}

extern "C" void kernel_launch(void* const* d_in, const int* in_sizes, int n_in,
                              void* d_out, int out_size, void* d_ws, size_t ws_size,
                              hipStream_t stream)
{
    const float* x       = (const float*)d_in[0];
    const int*   eidx    = (const int*)  d_in[1];
    const float* W_gat   = (const float*)d_in[2];
    const float* b_gat   = (const float*)d_in[3];
    const float* att_src = (const float*)d_in[4];
    const float* att_dst = (const float*)d_in[5];
    const float* W_lin   = (const float*)d_in[6];
    const float* b_lin   = (const float*)d_in[7];
    float* out = (float*)d_out;

    char* p = (char*)d_ws;
    auto alloc = [&](size_t bytes){ void* r = (void*)p; p += (bytes + 255) & ~(size_t)255; return r; };
    bf16*  Wg_bf  = (bf16*) alloc((size_t)KIN*HC*2);     // 1 MB
    bf16*  Wl_t   = (bf16*) alloc((size_t)NOUT*HC*2);    // 4 MB
    bf16*  WcT    = (bf16*) alloc((size_t)NOUT*YW*2);    // 1 MB
    bf16*  Ybuf   = (bf16*) alloc((size_t)NN*YW*2);      // 16.4 MB
    float* v      = (float*)alloc((size_t)KIN*16*4);
    float* a_src  = (float*)alloc((size_t)NN*NH*4);
    float* a_dst  = (float*)alloc((size_t)NN*NH*4);
    int*   offs   = (int*)  alloc((size_t)(NN+1)*4);
    int*   esrc   = (int*)  alloc((size_t)NE2*4);
    // zero-init group (contiguous; each size a 256-multiple)
    int*   counts = (int*)  alloc((size_t)NN*4);
    int*   cursors= (int*)  alloc((size_t)NN*4);
    float* b_eff  = (float*)alloc((size_t)NOUT*4);
    if ((size_t)(p - (char*)d_ws) > ws_size) return;

    hipMemsetAsync(counts, 0, (size_t)2*NN*4 + NOUT*4, stream);  // counts+cursors+b_eff
    k_phaseA<<<PHA_NB, 256, 0, stream>>>(W_lin, b_gat, W_gat, att_src, att_dst,
                                         eidx, Wl_t, b_eff, Wg_bf, v, counts);
    k_phaseB<<<65, 256, 0, stream>>>(Wl_t, Wg_bf, WcT, counts, offs);
    k_phaseC<<<PHC_NB, 256, 0, stream>>>(eidx, offs, cursors, esrc, x, v, a_src, a_dst);
    k_agg<<<NN/4, 256, 0, stream>>>(offs, esrc, a_src, a_dst, x, Ybuf);
    k_gemm64<<<dim3(NN/64, NOUT/128), 256, 0, stream>>>(Ybuf, WcT, b_eff, b_lin, out);
}

// Round 14
// 146.736 us; speedup vs baseline: 3.1621x; 1.0055x over previous
//
#include <hip/hip_runtime.h>
#include <hip/hip_bf16.h>
#include <type_traits>

#define NN   8000
#define NE   64000
#define NE2  72000   // edges + self loops
#define NH   8
#define OC   512
#define HC   4096    // NH*OC
#define KIN  128
#define NOUT 512
#define YW   1024    // NH*KIN
#define NEG_SLOPE 0.2f

using bf16 = __hip_bfloat16;
typedef float  f32x4  __attribute__((ext_vector_type(4)));
typedef __bf16 bf16x8 __attribute__((ext_vector_type(8)));

static __device__ __forceinline__ void gld_lds16(const bf16* g, bf16* l){
    __builtin_amdgcn_global_load_lds(
        (const __attribute__((address_space(1))) unsigned int*)g,
        (__attribute__((address_space(3))) unsigned int*)l, 16, 0, 0);
}

struct Acc24 { f32x4 a[2][4]; };

// 64x128 MFMA tile, LDS double-buffered, both operands bf16 k-contiguous.
static __device__ __forceinline__ void gemm64x128(
    const bf16* __restrict__ A, int lda, const bf16* __restrict__ BT, int ldb,
    int K, bf16* sA, bf16* sB, int tid, Acc24& acc)
{
    const int lane = tid & 63;
    const int w    = tid >> 6;
    const int wm   = w >> 1, wn = w & 1;
    const int m16  = lane & 15, q = lane >> 4;
    const int rA = tid >> 2,  kA = (tid & 3) * 8;
    const int cB0 = tid, cB1 = 256 + tid;
    const int rB0 = cB0 >> 2, kB0 = (cB0 & 3) * 8;
    const int rB1 = cB1 >> 2, kB1 = (cB1 & 3) * 8;
    const size_t gA  = (size_t)rA  * lda + kA;
    const size_t gB0 = (size_t)rB0 * ldb + kB0;
    const size_t gB1 = (size_t)rB1 * ldb + kB1;

    #pragma unroll
    for (int i=0;i<2;++i)
        #pragma unroll
        for (int j=0;j<4;++j)
            #pragma unroll
            for (int r=0;r<4;++r) acc.a[i][j][r] = 0.f;

    gld_lds16(A  + gA,  sA + tid*8);
    gld_lds16(BT + gB0, sB + cB0*8);
    gld_lds16(BT + gB1, sB + cB1*8);
    __syncthreads();

    const int nIter = K / 32;
    for (int it = 0; it < nIter; ++it){
        const int cur = it & 1, nxt = cur ^ 1;
        bf16x8 af[2], bfr[4];
        #pragma unroll
        for (int i=0;i<2;++i)
            af[i]  = *(const bf16x8*)(const void*)(sA + cur*64*32 + ((wm*32 + i*16 + m16)*32 + q*8));
        #pragma unroll
        for (int j=0;j<4;++j)
            bfr[j] = *(const bf16x8*)(const void*)(sB + cur*128*32 + ((wn*64 + j*16 + m16)*32 + q*8));
        if (it + 1 < nIter){
            int ko = (it+1) * 32;
            gld_lds16(A  + gA  + ko, sA + nxt*64*32 + tid*8);
            gld_lds16(BT + gB0 + ko, sB + nxt*128*32 + cB0*8);
            gld_lds16(BT + gB1 + ko, sB + nxt*128*32 + cB1*8);
        }
        #pragma unroll
        for (int i=0;i<2;++i)
            #pragma unroll
            for (int j=0;j<4;++j)
                acc.a[i][j] = __builtin_amdgcn_mfma_f32_16x16x32_bf16(af[i], bfr[j], acc.a[i][j], 0, 0, 0);
        __syncthreads();
    }
}

// ================= phase A: independent preprocessing =================
// [0,128): W_gat->bf16 (Wg_ext rows 0..127) + v[k][o]
// [128,130): b_gat->bf16 (Wg_ext row 128)
// [130,412): edge dst count
#define VSRC_NB   128
#define BCVT_BASE 128
#define CNT_BASE  130
#define PHA_NB    412

__global__ __launch_bounds__(256) void k_phaseA(
    const float* __restrict__ b_gat, const float* __restrict__ W_gat,
    const float* __restrict__ att_src, const float* __restrict__ att_dst,
    const int* __restrict__ eidx,
    bf16* __restrict__ Wg_ext, float* __restrict__ v,
    int* __restrict__ counts)
{
    const int bid = blockIdx.x;
    const int tid = threadIdx.x;

    if (bid < VSRC_NB){
        int k = bid;
        int lane = tid & 63, g = tid >> 6;
        for (int hh = g; hh < NH; hh += 4){
            const float* wp = W_gat + (size_t)k*HC + hh*OC;
            bf16*        wb = Wg_ext + (size_t)k*HC + hh*OC;
            const float* as = att_src + hh*OC;
            const float* ad = att_dst + hh*OC;
            float ss = 0.f, sd = 0.f;
            #pragma unroll
            for (int c0=0; c0<OC; c0+=64){
                float wv = wp[c0+lane];
                wb[c0+lane] = __float2bfloat16(wv);
                ss = fmaf(wv, as[c0+lane], ss);
                sd = fmaf(wv, ad[c0+lane], sd);
            }
            #pragma unroll
            for (int off=32; off; off>>=1){
                ss += __shfl_down(ss, off);
                sd += __shfl_down(sd, off);
            }
            if (lane == 0){
                v[k*16 + hh]     = ss;
                v[k*16 + 8 + hh] = sd;
            }
        }
    } else if (bid < CNT_BASE){
        // b_gat fp32[4096] -> Wg_ext row 128
        int idx = (bid - BCVT_BASE)*2048 + tid*8;
        float4 v0 = *(const float4*)(b_gat + idx);
        float4 v1 = *(const float4*)(b_gat + idx + 4);
        bf16x8 o;
        o[0]=(__bf16)v0.x; o[1]=(__bf16)v0.y; o[2]=(__bf16)v0.z; o[3]=(__bf16)v0.w;
        o[4]=(__bf16)v1.x; o[5]=(__bf16)v1.y; o[6]=(__bf16)v1.z; o[7]=(__bf16)v1.w;
        *(bf16x8*)(void*)(Wg_ext + (size_t)128*HC + idx) = o;
    } else {
        int e = (bid - CNT_BASE)*256 + tid;
        if (e < NE2){
            int dst = (e < NE) ? eidx[NE + e] : (e - NE);
            atomicAdd(&counts[dst], 1);
        }
    }
}

// ================= phase B: Wc GEMM w/ in-kernel W_lin transpose (96 blocks) + scan =========
// A = Wg_ext[129][HC] (rows k' 0..128; row 128 = b_gat). Per head: K = 512 (head's c-slice).
// D[k'][o] = sum_c Wg_ext[k'][h*512+c] * W_lin[h*512+c][o]
// rows<128 -> WcT[o][h*128+k']; row 128 -> atomicAdd b_eff[o].
#define PB_GEMM_NB 96

__global__ __launch_bounds__(256) void k_phaseB(
    const bf16* __restrict__ Wg_ext, const float* __restrict__ W_lin,
    bf16* __restrict__ WcT, float* __restrict__ b_eff,
    const int* __restrict__ counts, int* __restrict__ offsets)
{
    __shared__ __align__(16) bf16 sA[64*32];    // 4 KB
    __shared__ __align__(16) bf16 sB[128*32];   // 8 KB  (sB[o_local][c_local])
    __shared__ int part[256];
    const int bid = blockIdx.x;
    const int tid = threadIdx.x;

    if (bid == PB_GEMM_NB){
        // ---- prefix scan counts -> offsets ----
        int t = tid;
        int base = t*32;
        int s = 0;
        for (int u=0;u<32;++u){ int i = base+u; if (i<NN) s += counts[i]; }
        part[t] = s;
        __syncthreads();
        for (int off=1; off<256; off<<=1){
            int vv = (t>=off) ? part[t-off] : 0;
            __syncthreads();
            part[t] += vv;
            __syncthreads();
        }
        int run = (t==0) ? 0 : part[t-1];
        for (int u=0;u<32;++u){
            int i = base+u;
            if (i<NN){ offsets[i] = run; run += counts[i]; }
        }
        if (t == 255) offsets[NN] = run;
        return;
    }

    const int head = bid / 12;
    const int rem  = bid % 12;
    const int m0   = (rem >> 2) * 64;      // k'-tile: 0,64,128
    const int n0   = (rem & 3) * 128;      // o-tile
    const int lane = tid & 63;
    const int w = tid >> 6, wm = w >> 1, wn = w & 1;
    const int m16 = lane & 15, q = lane >> 4;

    // A staging: 64 rows x 32c per iter, 8 bf16/thread (row clamped to 128)
    const int rA = tid >> 2, kA = (tid & 3) * 8;
    const int arow = min(m0 + rA, 128);
    const bf16* Abase = Wg_ext + (size_t)arow*HC + head*OC + kA;

    f32x4 acc[2][4];
    #pragma unroll
    for (int i=0;i<2;++i)
        #pragma unroll
        for (int j=0;j<4;++j)
            #pragma unroll
            for (int r=0;r<4;++r) acc[i][j][r] = 0.f;

    for (int kc = 0; kc < OC; kc += 32){
        __syncthreads();   // prev iter's LDS reads complete
        gld_lds16(Abase + kc, sA + tid*8);
        // B stage: W_lin rows (head*OC+kc+r), cols n0..n0+127 -> sB[o][c] bf16
        #pragma unroll
        for (int u=0; u<4; ++u){
            int idx = tid*4 + u;              // 0..1023
            int r    = idx >> 5;              // c_local 0..31
            int gcol = (idx & 31) * 4;        // o_local group
            const float* src = W_lin + (size_t)(head*OC + kc + r)*NOUT + n0 + gcol;
            float4 vv = *(const float4*)src;
            sB[(gcol+0)*32 + r] = __float2bfloat16(vv.x);
            sB[(gcol+1)*32 + r] = __float2bfloat16(vv.y);
            sB[(gcol+2)*32 + r] = __float2bfloat16(vv.z);
            sB[(gcol+3)*32 + r] = __float2bfloat16(vv.w);
        }
        __syncthreads();   // staging complete (incl. vmcnt drain for gld_lds)
        bf16x8 af[2], bfr[4];
        #pragma unroll
        for (int i=0;i<2;++i)
            af[i]  = *(const bf16x8*)(const void*)(sA + ((wm*32 + i*16 + m16)*32 + q*8));
        #pragma unroll
        for (int j=0;j<4;++j)
            bfr[j] = *(const bf16x8*)(const void*)(sB + ((wn*64 + j*16 + m16)*32 + q*8));
        #pragma unroll
        for (int i=0;i<2;++i)
            #pragma unroll
            for (int j=0;j<4;++j)
                acc[i][j] = __builtin_amdgcn_mfma_f32_16x16x32_bf16(af[i], bfr[j], acc[i][j], 0, 0, 0);
    }

    // writeout: D rows = k' (m), cols = o (n)
    #pragma unroll
    for (int i=0;i<2;++i){
        int row_base = m0 + wm*32 + i*16 + q*4;
        #pragma unroll
        for (int j=0;j<4;++j){
            int col = n0 + wn*64 + j*16 + m16;
            if (row_base + 3 < 128){
                ushort4 pk;
                bf16 b0 = __float2bfloat16(acc[i][j][0]);
                bf16 b1 = __float2bfloat16(acc[i][j][1]);
                bf16 b2 = __float2bfloat16(acc[i][j][2]);
                bf16 b3 = __float2bfloat16(acc[i][j][3]);
                pk.x = *(unsigned short*)&b0; pk.y = *(unsigned short*)&b1;
                pk.z = *(unsigned short*)&b2; pk.w = *(unsigned short*)&b3;
                *reinterpret_cast<ushort4*>(WcT + (size_t)col*YW + head*KIN + row_base) = pk;
            } else {
                #pragma unroll
                for (int r=0;r<4;++r){
                    int row = row_base + r;
                    if (row < 128)
                        WcT[(size_t)col*YW + head*KIN + row] = __float2bfloat16(acc[i][j][r]);
                    else if (row == 128)
                        atomicAdd(b_eff + col, acc[i][j][r]);
                }
            }
        }
    }
}

// ================= phase C: CSR fill (282) + attn2 (500) (round-13 verbatim) =========
#define FILL_NB 282
#define PHC_NB  782

__global__ __launch_bounds__(256) void k_phaseC(
    const int* __restrict__ eidx, const int* __restrict__ offsets,
    int* __restrict__ cursors, int* __restrict__ esrc,
    const float* __restrict__ x, const float* __restrict__ v,
    float* __restrict__ a_src, float* __restrict__ a_dst)
{
    __shared__ __align__(16) float smem[16*132*2];
    const int bid = blockIdx.x;
    const int tid = threadIdx.x;

    if (bid < FILL_NB){
        int e = bid*256 + tid;
        if (e < NE2){
            int src, dst;
            if (e < NE){ src = eidx[e]; dst = eidx[NE+e]; } else { src = dst = e - NE; }
            int pos = atomicAdd(&cursors[dst], 1);
            esrc[offsets[dst] + pos] = src;
        }
        return;
    }
    float (*xs)[132] = (float(*)[132])smem;
    float (*vt)[132] = (float(*)[132])(smem + 16*132);
    int node0 = (bid - FILL_NB) * 16;
    {
        const float* xg = x + (size_t)node0*KIN;
        int row = tid >> 4, co = (tid & 15) * 8;
        float4 v0 = *(const float4*)(xg + row*KIN + co);
        float4 v1 = *(const float4*)(xg + row*KIN + co + 4);
        *(float4*)&xs[row][co]     = v0;
        *(float4*)&xs[row][co + 4] = v1;
    }
    {
        int base = tid*8;
        #pragma unroll
        for (int j=0;j<8;++j){
            int idx = base + j;
            vt[idx & 15][idx >> 4] = v[idx];
        }
    }
    __syncthreads();
    int ln = tid >> 4, o = tid & 15;
    float acc = 0.f;
    #pragma unroll
    for (int k0=0;k0<KIN;k0+=4){
        float4 xv = *(const float4*)&xs[ln][k0];
        float4 vv = *(const float4*)&vt[o][k0];
        acc += xv.x*vv.x + xv.y*vv.y + xv.z*vv.z + xv.w*vv.w;
    }
    int node = node0 + ln;
    if (o < 8) a_src[node*NH + o]     = acc;
    else       a_dst[node*NH + o - 8] = acc;
}

// ================= Y aggregation (round-13 verbatim) =========
__global__ __launch_bounds__(256) void k_agg(const int* __restrict__ offs,
    const int* __restrict__ esrc, const float* __restrict__ a_src,
    const float* __restrict__ a_dst, const float* __restrict__ x,
    bf16* __restrict__ Y)
{
    int node = blockIdx.x*4 + (threadIdx.x >> 6);
    int lane = threadIdx.x & 63;
    int s0 = offs[node], s1 = offs[node+1];
    int g = lane >> 3, h = lane & 7;
    float adl = a_dst[node*NH + h];
    float m = -1e30f, sum = 0.f;
    for (int e = s0 + g; e < s1; e += 8){
        float l = a_src[esrc[e]*NH + h] + adl;
        l = l > 0.f ? l : NEG_SLOPE*l;
        float mn = fmaxf(m, l);
        sum = sum*__expf(m - mn) + __expf(l - mn);
        m = mn;
    }
    #pragma unroll
    for (int d=8; d<64; d<<=1){
        float mo = __shfl_xor(m, d);
        float so = __shfl_xor(sum, d);
        float mn = fmaxf(m, mo);
        sum = sum*__expf(m - mn) + so*__expf(mo - mn);
        m = mn;
    }
    float inv = 1.f / (sum + 1e-16f);
    float acc[16];
    #pragma unroll
    for (int j=0;j<16;++j) acc[j] = 0.f;
    for (int s=s0; s<s1; ++s){
        int src = esrc[s];
        float wl = 0.f;
        if (lane < 8){
            float l = a_src[src*NH + lane] + adl;
            l = l > 0.f ? l : NEG_SLOPE*l;
            wl = __expf(l - m) * inv;
        }
        float2 xv = *(const float2*)(x + (size_t)src*KIN + lane*2);
        #pragma unroll
        for (int hh=0; hh<8; ++hh){
            float wh = __shfl(wl, hh);
            acc[hh*2]   = fmaf(wh, xv.x, acc[hh*2]);
            acc[hh*2+1] = fmaf(wh, xv.y, acc[hh*2+1]);
        }
    }
    bf16* yp = Y + (size_t)node*YW + lane*2;
    #pragma unroll
    for (int hh=0; hh<8; ++hh){
        bf16 b0 = __float2bfloat16(acc[hh*2]);
        bf16 b1 = __float2bfloat16(acc[hh*2+1]);
        ushort2 pk;
        pk.x = *(unsigned short*)&b0;
        pk.y = *(unsigned short*)&b1;
        *reinterpret_cast<ushort2*>(yp + hh*KIN) = pk;
    }
}

// ================= final GEMM: out = Y @ WcT^T + b_eff + b_lin (round-13 verbatim) ===
__global__ __launch_bounds__(256) void k_gemm64(
    const bf16* __restrict__ A, const bf16* __restrict__ BT,
    const float* __restrict__ b_eff, const float* __restrict__ b_lin,
    float* __restrict__ C)
{
    __shared__ __align__(16) char smem_raw[24576];
    bf16* sA = (bf16*)smem_raw;
    bf16* sB = (bf16*)(smem_raw + 8192);
    const int tid = threadIdx.x;
    int m0 = blockIdx.x * 64;
    int n0 = blockIdx.y * 128;
    Acc24 acc;
    gemm64x128(A + (size_t)m0*YW, YW, BT + (size_t)n0*YW, YW, YW, sA, sB, tid, acc);
    const int lane = tid & 63;
    const int w = tid >> 6, wm = w >> 1, wn = w & 1;
    const int m16 = lane & 15, q = lane >> 4;
    #pragma unroll
    for (int i=0;i<2;++i){
        int row_base = m0 + wm*32 + i*16 + q*4;
        #pragma unroll
        for (int j=0;j<4;++j){
            int col = n0 + wn*64 + j*16 + m16;
            float bval = b_eff[col] + b_lin[col];
            #pragma unroll
            for (int r=0;r<4;++r)
                C[(size_t)(row_base + r)*NOUT + col] = acc.a[i][j][r] + bval;
        }
    }
}

extern "C" void kernel_launch(void* const* d_in, const int* in_sizes, int n_in,
                              void* d_out, int out_size, void* d_ws, size_t ws_size,
                              hipStream_t stream)
{
    const float* x       = (const float*)d_in[0];
    const int*   eidx    = (const int*)  d_in[1];
    const float* W_gat   = (const float*)d_in[2];
    const float* b_gat   = (const float*)d_in[3];
    const float* att_src = (const float*)d_in[4];
    const float* att_dst = (const float*)d_in[5];
    const float* W_lin   = (const float*)d_in[6];
    const float* b_lin   = (const float*)d_in[7];
    float* out = (float*)d_out;

    char* p = (char*)d_ws;
    auto alloc = [&](size_t bytes){ void* r = (void*)p; p += (bytes + 255) & ~(size_t)255; return r; };
    bf16*  Wg_ext = (bf16*) alloc((size_t)129*HC*2);     // 1.06 MB (row 128 = b_gat)
    bf16*  WcT    = (bf16*) alloc((size_t)NOUT*YW*2);    // 1 MB
    bf16*  Ybuf   = (bf16*) alloc((size_t)NN*YW*2);      // 16.4 MB
    float* v      = (float*)alloc((size_t)KIN*16*4);
    float* a_src  = (float*)alloc((size_t)NN*NH*4);
    float* a_dst  = (float*)alloc((size_t)NN*NH*4);
    int*   offs   = (int*)  alloc((size_t)(NN+1)*4);
    int*   esrc   = (int*)  alloc((size_t)NE2*4);
    // zero-init group (contiguous)
    int*   counts = (int*)  alloc((size_t)NN*4);
    int*   cursors= (int*)  alloc((size_t)NN*4);
    float* b_eff  = (float*)alloc((size_t)NOUT*4);
    if ((size_t)(p - (char*)d_ws) > ws_size) return;

    hipMemsetAsync(counts, 0, (size_t)2*NN*4 + NOUT*4, stream);  // counts+cursors+b_eff
    k_phaseA<<<PHA_NB, 256, 0, stream>>>(b_gat, W_gat, att_src, att_dst,
                                         eidx, Wg_ext, v, counts);
    k_phaseB<<<PB_GEMM_NB + 1, 256, 0, stream>>>(Wg_ext, W_lin, WcT, b_eff, counts, offs);
    k_phaseC<<<PHC_NB, 256, 0, stream>>>(eidx, offs, cursors, esrc, x, v, a_src, a_dst);
    k_agg<<<NN/4, 256, 0, stream>>>(offs, esrc, a_src, a_dst, x, Ybuf);
    k_gemm64<<<dim3(NN/64, NOUT/128), 256, 0, stream>>>(Ybuf, WcT, b_eff, b_lin, out);
}